// Round 21
// baseline (153.877 us; speedup 1.0000x reference)
//
#include <hip/hip_runtime.h>
#include <cfloat>

#define N_TOK   32768
#define DIM     64
#define K_CODES 8192
#define NCHK    64                 // 128-code chunks
#define TPB     128                // tokens per select block
#define CHB     32                 // chunks per select block (2-way split)

#define IDX_OFF  (N_TOK * DIM)
#define LOSS_OFF (N_TOK * DIM + N_TOK)

// ws layout (float units): esq 8192 + ehiT 262144 (1MB bf16) + parts + gkey
#define WS_ESQ   0
#define WS_EHIT  8192
#define WS_PART  270336
#define WS_GKEY  270464            // 32768 x u64 = 65536 float slots (8B aligned)
// out zq-region scratch (dead until vq_finish):
//   eT (f32 transposed emb) at out+0 : 524288 floats
//   Mm (bf16-up, [chunk][token]) at out+524288 : 2097152 ushorts

#define MRG   2e-5f     // strict slack: bound < every computed fl-d in chunk
#define DINIT 6e-5f     // init slack (covers esq_max + fl-roundings + Mm bf16-up ulp)

typedef __attribute__((ext_vector_type(8)))  short bf16x8;
typedef __attribute__((ext_vector_type(16))) float f32x16;

__device__ inline ushort f2bf(float x) {          // round-to-nearest-even
    unsigned u = __float_as_uint(x);
    return (ushort)((u + 0x7FFFu + ((u >> 16) & 1u)) >> 16);
}
__device__ inline float bf2f(ushort h) { return __uint_as_float(((unsigned)h) << 16); }
__device__ inline ushort f2bf_up(float x) {       // round toward +inf (conservative)
    unsigned u = __float_as_uint(x);
    return (x >= 0.0f) ? (ushort)((u + 0xFFFFu) >> 16) : (ushort)(u >> 16);
}
// sortable pack: lexicographic (d, idx) min == np argmin first-occurrence
__device__ inline unsigned long long packdi(float d, int i) {
    unsigned u = __float_as_uint(d);
    u ^= (u & 0x80000000u) ? 0xFFFFFFFFu : 0x80000000u;
    return ((unsigned long long)u << 32) | (unsigned)i;
}

// ---------------------------------------------------------------------------
// e_sq[k] = numpy-pairwise sum of squares (bitwise np order) — proven R1-R20.
// ---------------------------------------------------------------------------
__global__ __launch_bounds__(256) void esq_kernel(const float* __restrict__ emb,
                                                  float* __restrict__ esq) {
#pragma clang fp contract(off)
    const int tid = threadIdx.x;
    const int q = tid & 7;
    const int code = blockIdx.x * 32 + (tid >> 3);
    const float* row = emb + code * DIM;
    float x = row[q];
    float r = x * x;
#pragma unroll
    for (int m = 1; m < 8; ++m) {
        float y = row[q + 8 * m];
        float sq = y * y;
        r = r + sq;
    }
    r = r + __shfl_xor(r, 1, 64);
    r = r + __shfl_xor(r, 2, 64);
    r = r + __shfl_xor(r, 4, 64);
    if (q == 0) esq[code] = r;
}

// ---------------------------------------------------------------------------
// Pack: ehiT = bf16 e in MFMA-A-fragment order (coalesced b128 A-loads);
// eT = exact f32 transpose eT[j*8192+k] = emb[k][j] (coalesced streaming).
// ---------------------------------------------------------------------------
__global__ __launch_bounds__(256) void pack2(const float* __restrict__ emb,
                                             ushort* __restrict__ ehiT,
                                             float* __restrict__ eT) {
#pragma clang fp contract(off)
    const int k = blockIdx.x * 256 + threadIdx.x;   // 8192 codes
    float v[64];
    {
        const float4* ep = (const float4*)(emb + (size_t)k * DIM);
#pragma unroll
        for (int i = 0; i < 16; ++i) {
            const float4 a = ep[i];
            v[4 * i] = a.x; v[4 * i + 1] = a.y; v[4 * i + 2] = a.z; v[4 * i + 3] = a.w;
        }
    }
#pragma unroll
    for (int j = 0; j < 64; ++j) eT[(size_t)j * K_CODES + k] = v[j];
    const int sc = k >> 7, lc = k & 127;
#pragma unroll
    for (int q = 0; q < 4; ++q)
#pragma unroll
        for (int h = 0; h < 2; ++h) {
            bf16x8 o;
#pragma unroll
            for (int e = 0; e < 8; ++e) o[e] = (short)f2bf(v[16 * q + 8 * h + e]);
            *(bf16x8*)(ehiT + ((((size_t)sc * 4 + q) * 2 + h) * 128 + lc) * 8) = o;
        }
}

// ---------------------------------------------------------------------------
// MFMA sweep v4 (unchanged from R20, passed): z_hi only, g-level A dbuf.
// ---------------------------------------------------------------------------
__global__ __launch_bounds__(256, 2) void vq_mfma(const float* __restrict__ hid,
                                                  const ushort* __restrict__ ehiT,
                                                  ushort* __restrict__ Mm) {
#pragma clang fp contract(off)
    const int tid = threadIdx.x;
    const int lane = tid & 63;
    const int w = tid >> 6;
    const int h = lane >> 5;
    const int t0 = blockIdx.x * 64;

    bf16x8 z_hi[2][4];
#pragma unroll
    for (int ts = 0; ts < 2; ++ts)
#pragma unroll
    for (int q = 0; q < 4; ++q) {
        const float* zp = hid + (size_t)(t0 + 32 * ts + (lane & 31)) * DIM + 16 * q + 8 * h;
        const float4 u0 = *(const float4*)zp;
        const float4 u1 = *(const float4*)(zp + 4);
        const float zz[8] = {u0.x, u0.y, u0.z, u0.w, u1.x, u1.y, u1.z, u1.w};
        bf16x8 hv;
#pragma unroll
        for (int i = 0; i < 8; ++i) hv[i] = (short)f2bf(zz[i]);
        z_hi[ts][q] = hv;
    }

    f32x16 zc;
#pragma unroll
    for (int i = 0; i < 16; ++i) zc[i] = 0.0f;

#define ALOAD(SC, R, Q) (*(const bf16x8*)(ehiT + \
    ((((size_t)(SC) * 4 + (Q)) * 2 + h) * 128 + 32 * (R) + (lane & 31)) * 8))

    bf16x8 Aa[4][4], Ab[4][4];
#pragma unroll
    for (int r = 0; r < 4; ++r)
#pragma unroll
        for (int q = 0; q < 4; ++q) Aa[r][q] = ALOAD(w, r, q);

#define MFMA_G(CUR, NXT, G) { \
    const int sc = 4 * (G) + w; \
    const int scn = ((G) + 1 < 16) ? (4 * ((G) + 1) + w) : sc; \
    _Pragma("unroll") \
    for (int r = 0; r < 4; ++r) \
        _Pragma("unroll") \
        for (int q = 0; q < 4; ++q) NXT[r][q] = ALOAD(scn, r, q); \
    float wm0 = -3.0e38f, wm1 = -3.0e38f; \
    _Pragma("unroll") \
    for (int r = 0; r < 4; ++r) { \
        f32x16 d0 = __builtin_amdgcn_mfma_f32_32x32x16_bf16(CUR[r][0], z_hi[0][0], zc, 0, 0, 0); \
        f32x16 d1 = __builtin_amdgcn_mfma_f32_32x32x16_bf16(CUR[r][0], z_hi[1][0], zc, 0, 0, 0); \
        _Pragma("unroll") \
        for (int q = 1; q < 4; ++q) { \
            d0 = __builtin_amdgcn_mfma_f32_32x32x16_bf16(CUR[r][q], z_hi[0][q], d0, 0, 0, 0); \
            d1 = __builtin_amdgcn_mfma_f32_32x32x16_bf16(CUR[r][q], z_hi[1][q], d1, 0, 0, 0); \
        } \
        _Pragma("unroll") \
        for (int i = 0; i < 16; ++i) { \
            wm0 = fmaxf(wm0, d0[i]); \
            wm1 = fmaxf(wm1, d1[i]); \
        } \
    } \
    wm0 = fmaxf(wm0, __shfl_xor(wm0, 32, 64)); \
    wm1 = fmaxf(wm1, __shfl_xor(wm1, 32, 64)); \
    if (lane < 32) { \
        Mm[(size_t)sc * N_TOK + t0 + lane]      = f2bf_up(wm0); \
        Mm[(size_t)sc * N_TOK + t0 + 32 + lane] = f2bf_up(wm1); \
    } }

    for (int gg = 0; gg < 16; gg += 2) {
        MFMA_G(Aa, Ab, gg)
        MFMA_G(Ab, Aa, gg + 1)
    }
#undef MFMA_G
#undef ALOAD
}

// ---------------------------------------------------------------------------
// Exact selection v11 = R20's v10 split 2-way over chunk-space: block
// (tp,cb) = (bid>>1, bid&1) handles tokens tp*128..+128 x chunks
// [32cb,32cb+32) -> grid 512 = 2 blocks/CU = 4 waves/SIMD (R20 was
// latency-bound at 2). Fold via GLOBAL atomicMin(u64) on the same sortable
// (d,idx) key: lexicographic min is partition-order-independent == np
// first-occurrence. bD init scans all 64 chunks (identical in both blocks).
// All arithmetic byte-identical to R20.
// ---------------------------------------------------------------------------
__global__ __launch_bounds__(512, 2) void vq_select(const float* __restrict__ hid,
                                                    const float* __restrict__ eT,
                                                    const float* __restrict__ esq,
                                                    const ushort* __restrict__ Mm,
                                                    unsigned long long* __restrict__ gkey) {
#pragma clang fp contract(off)
    __shared__ float z_s[TPB][68];
    __shared__ float zsq_s[TPB];
    __shared__ float eps_s[TPB];
    __shared__ float bD_s[TPB];
    __shared__ float mxw[4][TPB];
    __shared__ unsigned long long m0_s[CHB];
    __shared__ unsigned long long m1_s[CHB];

    const int tid = threadIdx.x;
    const int lane = tid & 63;
    const int w = tid >> 6;                 // 0..7
    const int cb = blockIdx.x & 1;          // chunk half
    const int t0 = (blockIdx.x >> 1) * TPB;

    // ---- stage z into LDS ----
    {
        const int t = tid >> 2;                // 0..127
        const int j4 = (tid & 3) * 4;          // float4 index (4 per thread)
        const float4* src = (const float4*)(hid + (size_t)(t0 + t) * DIM);
        float4* dst = (float4*)(&z_s[t][0]);
#pragma unroll
        for (int i = 0; i < 4; ++i) dst[j4 + i] = src[j4 + i];
    }
    __syncthreads();

    // ---- phase 1a: partial Mm-max over ALL 64 chunks; zsq (threads 0..127) ----
    {
        const int token = tid & 127;
        const int cg = tid >> 7;               // 0..3
        float pm = bf2f(Mm[(size_t)(16 * cg) * N_TOK + t0 + token]);
#pragma unroll 5
        for (int c = 16 * cg + 1; c < 16 * cg + 16; ++c)
            pm = fmaxf(pm, bf2f(Mm[(size_t)c * N_TOK + t0 + token]));
        mxw[cg][token] = pm;
    }
    if (tid < TPB) {
        const float* zr = &z_s[tid][0];
        float r[8];
#pragma unroll
        for (int q = 0; q < 8; ++q) {
            float x = zr[q]; r[q] = x * x;
#pragma unroll
            for (int m = 1; m < 8; ++m) {
                float y = zr[q + 8 * m];
                float sq = y * y;
                r[q] = r[q] + sq;
            }
        }
        zsq_s[tid] = ((r[0] + r[1]) + (r[2] + r[3])) + ((r[4] + r[5]) + (r[6] + r[7]));
    }
    __syncthreads();
    if (tid < TPB) {
        const float mx = fmaxf(fmaxf(mxw[0][tid], mxw[1][tid]),
                               fmaxf(mxw[2][tid], mxw[3][tid]));
        const float zsq = zsq_s[tid];
        const float eps = sqrtf(zsq) * 4.2e-6f + 2e-7f;   // covers e-bf16 + z-bf16 (no lo)
        eps_s[tid] = eps;
        bD_s[tid] = zsq - 2.0f * mx + 2.0f * eps + DINIT;   // >= true best fl-d
    }
    __syncthreads();

    // ---- phase 1b: survivor masks for this wave's 4 chunks (ballot) ----
#pragma unroll
    for (int i = 0; i < 4; ++i) {
        const int lc = 4 * w + i;
        const int c = CHB * cb + lc;
        const float mA = bf2f(Mm[(size_t)c * N_TOK + t0 + lane]);
        const int sA = (fmaf(-2.0f, mA + eps_s[lane], zsq_s[lane]) - MRG) < bD_s[lane];
        const unsigned long long b0 = __ballot(sA);
        const float mB = bf2f(Mm[(size_t)c * N_TOK + t0 + 64 + lane]);
        const int sB = (fmaf(-2.0f, mB + eps_s[64 + lane], zsq_s[64 + lane]) - MRG) < bD_s[64 + lane];
        const unsigned long long b1 = __ballot(sB);
        if (lane == 0) { m0_s[lc] = b0; m1_s[lc] = b1; }
    }
    // no barrier: each wave reads only masks it wrote

    // ---- phase 2: paired eval, 2 tokens per pipelined e-stream ----
    for (int i = 0; i < 4; ++i) {
        const int lc = 4 * w + i;
        const int c = CHB * cb + lc;
        unsigned long long msk0 = m0_s[lc], msk1 = m1_s[lc];
        if (!(msk0 | msk1)) continue;
        const int k0 = c * 128 + 2 * lane;
        const float* eb = eT + k0;
        const float2 es2 = *(const float2*)(esq + k0);

        while (msk0 | msk1) {
            int G = 1;
            int tA, tB;
            if (msk0) { tA = __ffsll(msk0) - 1; msk0 &= msk0 - 1; }
            else      { tA = 64 + __ffsll(msk1) - 1; msk1 &= msk1 - 1; }
            tB = tA;
            if (msk0 | msk1) {
                G = 2;
                if (msk0) { tB = __ffsll(msk0) - 1; msk0 &= msk0 - 1; }
                else      { tB = 64 + __ffsll(msk1) - 1; msk1 &= msk1 - 1; }
            }
            const float4* zpA = (const float4*)(&z_s[tA][0]);
            const float4* zpB = (const float4*)(&z_s[tB][0]);

            float2 bA[8], bB[8];
            float aA0, aA1, aB0, aB1;
#define LOADG(B, G2) { _Pragma("unroll") \
    for (int j = 0; j < 8; ++j) \
        B[j] = *(const float2*)(eb + (size_t)(8 * (G2) + j) * K_CODES); }
#define FMAJ(Bj, vA, vB, COMP) \
    aA0 = fmaf(vA.COMP, Bj.x, aA0); aA1 = fmaf(vA.COMP, Bj.y, aA1); \
    aB0 = fmaf(vB.COMP, Bj.x, aB0); aB1 = fmaf(vB.COMP, Bj.y, aB1);
#define FMAG(B, G2) { \
    const float4 vA = zpA[2 * (G2)], vB = zpB[2 * (G2)]; \
    FMAJ(B[0], vA, vB, x) FMAJ(B[1], vA, vB, y) \
    FMAJ(B[2], vA, vB, z) FMAJ(B[3], vA, vB, w) \
    const float4 uA = zpA[2 * (G2) + 1], uB = zpB[2 * (G2) + 1]; \
    FMAJ(B[4], uA, uB, x) FMAJ(B[5], uA, uB, y) \
    FMAJ(B[6], uA, uB, z) FMAJ(B[7], uA, uB, w) }

            LOADG(bA, 0)
            LOADG(bB, 1)
            {   // group 0, j=0 peeled as mul (bitwise head of each chain)
                const float4 vA = zpA[0], vB = zpB[0];
                aA0 = vA.x * bA[0].x; aA1 = vA.x * bA[0].y;
                aB0 = vB.x * bA[0].x; aB1 = vB.x * bA[0].y;
                FMAJ(bA[1], vA, vB, y)
                FMAJ(bA[2], vA, vB, z)
                FMAJ(bA[3], vA, vB, w)
                const float4 uA = zpA[1], uB = zpB[1];
                FMAJ(bA[4], uA, uB, x)
                FMAJ(bA[5], uA, uB, y)
                FMAJ(bA[6], uA, uB, z)
                FMAJ(bA[7], uA, uB, w)
            }
            LOADG(bA, 2) FMAG(bB, 1)
            LOADG(bB, 3) FMAG(bA, 2)
            LOADG(bA, 4) FMAG(bB, 3)
            LOADG(bB, 5) FMAG(bA, 4)
            LOADG(bA, 6) FMAG(bB, 5)
            LOADG(bB, 7) FMAG(bA, 6)
            FMAG(bB, 7)
#undef LOADG
#undef FMAJ
#undef FMAG

#define FINISH(aX0, aX1, tX) { \
    const float zqX = zsq_s[tX]; \
    const float dX0 = fmaf(-2.0f, aX0, zqX + es2.x); \
    const float dX1 = fmaf(-2.0f, aX1, zqX + es2.y); \
    float dl = dX0; int il = k0; \
    if (dX1 < dl) { dl = dX1; il = k0 + 1; } \
    _Pragma("unroll") \
    for (int mm = 1; mm < 64; mm <<= 1) { \
        const float ov = __shfl_xor(dl, mm, 64); \
        const int   oi = __shfl_xor(il, mm, 64); \
        if (ov < dl || (ov == dl && oi < il)) { dl = ov; il = oi; } \
    } \
    if (lane == 0) atomicMin(&gkey[t0 + tX], packdi(dl, il)); }

            FINISH(aA0, aA1, tA)
            if (G > 1) FINISH(aB0, aB1, tB)
#undef FINISH
        }
    }
}

// ---------------------------------------------------------------------------
// Outputs: indices from gkey, z_q = h + (q - h), loss partials (proven form).
// ---------------------------------------------------------------------------
__global__ __launch_bounds__(256) void vq_finish(const float* __restrict__ hid,
                                                 const float* __restrict__ emb,
                                                 const unsigned long long* __restrict__ gkey,
                                                 float* __restrict__ out_zq,
                                                 float* __restrict__ out_idx,
                                                 float* __restrict__ partials) {
#pragma clang fp contract(off)
    __shared__ float lred[4];
    const int tid = threadIdx.x;
    const int t = blockIdx.x * 256 + tid;

    const int bi = (int)(gkey[t] & 0xFFFFFFFFull);
    out_idx[t] = (float)bi;

    const float4* q4 = (const float4*)(emb + (size_t)bi * DIM);
    const float4* h4 = (const float4*)(hid + (size_t)t * DIM);
    float4* o4 = (float4*)(out_zq + (size_t)t * DIM);
    float lsum = 0.f;
#pragma unroll
    for (int i = 0; i < 16; ++i) {
        const float4 q = q4[i];
        const float4 h = h4[i];
        float4 zq;
        float dx;
        dx = q.x - h.x; zq.x = h.x + dx; lsum += dx * dx;
        dx = q.y - h.y; zq.y = h.y + dx; lsum += dx * dx;
        dx = q.z - h.z; zq.z = h.z + dx; lsum += dx * dx;
        dx = q.w - h.w; zq.w = h.w + dx; lsum += dx * dx;
        o4[i] = zq;
    }

#pragma unroll
    for (int off = 32; off >= 1; off >>= 1) lsum += __shfl_xor(lsum, off, 64);
    const int wid = tid >> 6;
    if ((tid & 63) == 0) lred[wid] = lsum;
    __syncthreads();
    if (tid == 0) partials[blockIdx.x] = (lred[0] + lred[1]) + (lred[2] + lred[3]);
}

__global__ __launch_bounds__(128) void loss_kernel(const float* __restrict__ partials,
                                                   float* __restrict__ out_loss) {
#pragma clang fp contract(off)
    __shared__ float s[128];
    const int t = threadIdx.x;
    s[t] = partials[t];
    __syncthreads();
    for (int off = 64; off >= 1; off >>= 1) {
        if (t < off) s[t] = s[t] + s[t + off];
        __syncthreads();
    }
    if (t == 0) {
        const float m = s[0] * (1.0f / 2097152.0f);  // exact: /2^21
        out_loss[0] = m + 0.25f * m;
    }
}

extern "C" void kernel_launch(void* const* d_in, const int* in_sizes, int n_in,
                              void* d_out, int out_size, void* d_ws, size_t ws_size,
                              hipStream_t stream) {
    const float* hid = (const float*)d_in[0];
    const float* emb = (const float*)d_in[1];
    float* out = (float*)d_out;
    float* ws  = (float*)d_ws;
    float*  esq   = ws + WS_ESQ;
    ushort* ehiT  = (ushort*)(ws + WS_EHIT);
    float*  parts = ws + WS_PART;
    unsigned long long* gkey = (unsigned long long*)(ws + WS_GKEY);
    float*  eT    = out;                               // zq-region scratch
    ushort* Mm    = (ushort*)(out + 524288);           // zq-region scratch

    hipMemsetAsync(gkey, 0xFF, (size_t)N_TOK * sizeof(unsigned long long), stream);
    esq_kernel<<<K_CODES / 32, 256, 0, stream>>>(emb, esq);
    pack2<<<K_CODES / 256, 256, 0, stream>>>(emb, ehiT, eT);
    vq_mfma<<<N_TOK / 64, 256, 0, stream>>>(hid, ehiT, Mm);
    vq_select<<<(N_TOK / TPB) * 2, 512, 0, stream>>>(hid, eT, esq, Mm, gkey);
    vq_finish<<<N_TOK / 256, 256, 0, stream>>>(hid, emb, gkey, out, out + IDX_OFF, parts);
    loss_kernel<<<1, 128, 0, stream>>>(parts, out + LOSS_OFF);
}

// Round 22
// 132.396 us; speedup vs baseline: 1.1623x; 1.1623x over previous
//
#include <hip/hip_runtime.h>
#include <cfloat>

#define N_TOK   32768
#define DIM     64
#define K_CODES 8192
#define NCHK    64                 // 128-code chunks
#define TPB     128                // tokens per select block

#define IDX_OFF  (N_TOK * DIM)
#define LOSS_OFF (N_TOK * DIM + N_TOK)

// ---- fallback (R20) ws layout, float units ----
#define WS_ESQ   0
#define WS_EHIT  8192
#define WS_PART  270336            // 128 floats
// fallback out-region scratch: eT at out+0 (524288 f), Mm at out+524288 (2M ushorts)

// ---- fused ws layout, float units ----
#define W2_ESQ   0
#define W2_EHIT  8192              // 524288 ushorts = 262144 float slots
#define W2_ET    270336            // 524288 floats
#define W2_MM    794624            // 2097152 ushorts = 1048576 float slots
#define W2_PART  1843200           // 256 floats
#define W2_TOTAL 1843456           // floats -> 7,373,824 bytes

#define MRG   2e-5f     // strict slack: bound < every computed fl-d in chunk
#define DINIT 6e-5f     // init slack (covers esq_max + fl-roundings + Mm bf16-up ulp)

typedef __attribute__((ext_vector_type(8)))  short bf16x8;
typedef __attribute__((ext_vector_type(16))) float f32x16;

__device__ inline ushort f2bf(float x) {          // round-to-nearest-even
    unsigned u = __float_as_uint(x);
    return (ushort)((u + 0x7FFFu + ((u >> 16) & 1u)) >> 16);
}
__device__ inline float bf2f(ushort h) { return __uint_as_float(((unsigned)h) << 16); }
__device__ inline ushort f2bf_up(float x) {       // round toward +inf (conservative)
    unsigned u = __float_as_uint(x);
    return (x >= 0.0f) ? (ushort)((u + 0xFFFFu) >> 16) : (ushort)(u >> 16);
}
// sortable pack: lexicographic (d, idx) min == np argmin first-occurrence
__device__ inline unsigned long long packdi(float d, int i) {
    unsigned u = __float_as_uint(d);
    u ^= (u & 0x80000000u) ? 0xFFFFFFFFu : 0x80000000u;
    return ((unsigned long long)u << 32) | (unsigned)i;
}

// ---------------------------------------------------------------------------
// e_sq[k] = numpy-pairwise sum of squares (bitwise np order) — proven R1-R21.
// ---------------------------------------------------------------------------
__global__ __launch_bounds__(256) void esq_kernel(const float* __restrict__ emb,
                                                  float* __restrict__ esq) {
#pragma clang fp contract(off)
    const int tid = threadIdx.x;
    const int q = tid & 7;
    const int code = blockIdx.x * 32 + (tid >> 3);
    const float* row = emb + code * DIM;
    float x = row[q];
    float r = x * x;
#pragma unroll
    for (int m = 1; m < 8; ++m) {
        float y = row[q + 8 * m];
        float sq = y * y;
        r = r + sq;
    }
    r = r + __shfl_xor(r, 1, 64);
    r = r + __shfl_xor(r, 2, 64);
    r = r + __shfl_xor(r, 4, 64);
    if (q == 0) esq[code] = r;
}

// ---------------------------------------------------------------------------
// Pack: ehiT = bf16 e in MFMA-A-fragment order; eT = exact f32 transpose.
// ---------------------------------------------------------------------------
__global__ __launch_bounds__(256) void pack2(const float* __restrict__ emb,
                                             ushort* __restrict__ ehiT,
                                             float* __restrict__ eT) {
#pragma clang fp contract(off)
    const int k = blockIdx.x * 256 + threadIdx.x;   // 8192 codes
    float v[64];
    {
        const float4* ep = (const float4*)(emb + (size_t)k * DIM);
#pragma unroll
        for (int i = 0; i < 16; ++i) {
            const float4 a = ep[i];
            v[4 * i] = a.x; v[4 * i + 1] = a.y; v[4 * i + 2] = a.z; v[4 * i + 3] = a.w;
        }
    }
#pragma unroll
    for (int j = 0; j < 64; ++j) eT[(size_t)j * K_CODES + k] = v[j];
    const int sc = k >> 7, lc = k & 127;
#pragma unroll
    for (int q = 0; q < 4; ++q)
#pragma unroll
        for (int h = 0; h < 2; ++h) {
            bf16x8 o;
#pragma unroll
            for (int e = 0; e < 8; ++e) o[e] = (short)f2bf(v[16 * q + 8 * h + e]);
            *(bf16x8*)(ehiT + ((((size_t)sc * 4 + q) * 2 + h) * 128 + lc) * 8) = o;
        }
}

// ---------------------------------------------------------------------------
// MFMA sweep v4 (unchanged from R20, passed): z_hi only, g-level A dbuf.
// ---------------------------------------------------------------------------
__global__ __launch_bounds__(256, 2) void vq_mfma(const float* __restrict__ hid,
                                                  const ushort* __restrict__ ehiT,
                                                  ushort* __restrict__ Mm) {
#pragma clang fp contract(off)
    const int tid = threadIdx.x;
    const int lane = tid & 63;
    const int w = tid >> 6;
    const int h = lane >> 5;
    const int t0 = blockIdx.x * 64;

    bf16x8 z_hi[2][4];
#pragma unroll
    for (int ts = 0; ts < 2; ++ts)
#pragma unroll
    for (int q = 0; q < 4; ++q) {
        const float* zp = hid + (size_t)(t0 + 32 * ts + (lane & 31)) * DIM + 16 * q + 8 * h;
        const float4 u0 = *(const float4*)zp;
        const float4 u1 = *(const float4*)(zp + 4);
        const float zz[8] = {u0.x, u0.y, u0.z, u0.w, u1.x, u1.y, u1.z, u1.w};
        bf16x8 hv;
#pragma unroll
        for (int i = 0; i < 8; ++i) hv[i] = (short)f2bf(zz[i]);
        z_hi[ts][q] = hv;
    }

    f32x16 zc;
#pragma unroll
    for (int i = 0; i < 16; ++i) zc[i] = 0.0f;

#define ALOAD(SC, R, Q) (*(const bf16x8*)(ehiT + \
    ((((size_t)(SC) * 4 + (Q)) * 2 + h) * 128 + 32 * (R) + (lane & 31)) * 8))

    bf16x8 Aa[4][4], Ab[4][4];
#pragma unroll
    for (int r = 0; r < 4; ++r)
#pragma unroll
        for (int q = 0; q < 4; ++q) Aa[r][q] = ALOAD(w, r, q);

#define MFMA_G(CUR, NXT, G) { \
    const int sc = 4 * (G) + w; \
    const int scn = ((G) + 1 < 16) ? (4 * ((G) + 1) + w) : sc; \
    _Pragma("unroll") \
    for (int r = 0; r < 4; ++r) \
        _Pragma("unroll") \
        for (int q = 0; q < 4; ++q) NXT[r][q] = ALOAD(scn, r, q); \
    float wm0 = -3.0e38f, wm1 = -3.0e38f; \
    _Pragma("unroll") \
    for (int r = 0; r < 4; ++r) { \
        f32x16 d0 = __builtin_amdgcn_mfma_f32_32x32x16_bf16(CUR[r][0], z_hi[0][0], zc, 0, 0, 0); \
        f32x16 d1 = __builtin_amdgcn_mfma_f32_32x32x16_bf16(CUR[r][0], z_hi[1][0], zc, 0, 0, 0); \
        _Pragma("unroll") \
        for (int q = 1; q < 4; ++q) { \
            d0 = __builtin_amdgcn_mfma_f32_32x32x16_bf16(CUR[r][q], z_hi[0][q], d0, 0, 0, 0); \
            d1 = __builtin_amdgcn_mfma_f32_32x32x16_bf16(CUR[r][q], z_hi[1][q], d1, 0, 0, 0); \
        } \
        _Pragma("unroll") \
        for (int i = 0; i < 16; ++i) { \
            wm0 = fmaxf(wm0, d0[i]); \
            wm1 = fmaxf(wm1, d1[i]); \
        } \
    } \
    wm0 = fmaxf(wm0, __shfl_xor(wm0, 32, 64)); \
    wm1 = fmaxf(wm1, __shfl_xor(wm1, 32, 64)); \
    if (lane < 32) { \
        Mm[(size_t)sc * N_TOK + t0 + lane]      = f2bf_up(wm0); \
        Mm[(size_t)sc * N_TOK + t0 + 32 + lane] = f2bf_up(wm1); \
    } }

    for (int gg = 0; gg < 16; gg += 2) {
        MFMA_G(Aa, Ab, gg)
        MFMA_G(Ab, Aa, gg + 1)
    }
#undef MFMA_G
#undef ALOAD
}

// ---------------------------------------------------------------------------
// Select core (R20 v10, proven): phases 1a/1b + paired pipelined eval +
// LDS atomicMin fold. FUSED=1 adds the vq_finish epilogue (zq/idx/loss from
// z_s — bitwise-identical per-token chains) so vq_finish is skipped.
// ---------------------------------------------------------------------------
template <int FUSED>
__global__ __launch_bounds__(512, 1) void vq_select_t(const float* __restrict__ hid,
                                                      const float* __restrict__ eT,
                                                      const float* __restrict__ esq,
                                                      const ushort* __restrict__ Mm,
                                                      const float* __restrict__ emb,
                                                      float* __restrict__ out_zq,
                                                      float* __restrict__ out_idx,
                                                      float* __restrict__ partials) {
#pragma clang fp contract(off)
    __shared__ float z_s[TPB][68];
    __shared__ float zsq_s[TPB];
    __shared__ float eps_s[TPB];
    __shared__ float bD_s[TPB];
    __shared__ float mxw[4][TPB];
    __shared__ unsigned long long key_s[TPB];
    __shared__ unsigned long long m0_s[NCHK];
    __shared__ unsigned long long m1_s[NCHK];
    __shared__ float lred[2];

    const int tid = threadIdx.x;
    const int lane = tid & 63;
    const int w = tid >> 6;                 // 0..7
    const int t0 = blockIdx.x * TPB;

    // ---- stage z into LDS; init keys ----
    {
        const int t = tid >> 2;                // 0..127
        const int j4 = (tid & 3) * 4;          // float4 index (4 per thread)
        const float4* src = (const float4*)(hid + (size_t)(t0 + t) * DIM);
        float4* dst = (float4*)(&z_s[t][0]);
#pragma unroll
        for (int i = 0; i < 4; ++i) dst[j4 + i] = src[j4 + i];
    }
    if (tid < TPB) key_s[tid] = ~0ull;
    __syncthreads();

    // ---- phase 1a: partial Mm-max (512 workers) and zsq (threads 0..127) ----
    {
        const int token = tid & 127;
        const int cg = tid >> 7;               // 0..3
        float pm = bf2f(Mm[(size_t)(16 * cg) * N_TOK + t0 + token]);
#pragma unroll 5
        for (int c = 16 * cg + 1; c < 16 * cg + 16; ++c)
            pm = fmaxf(pm, bf2f(Mm[(size_t)c * N_TOK + t0 + token]));
        mxw[cg][token] = pm;
    }
    if (tid < TPB) {
        const float* zr = &z_s[tid][0];
        float r[8];
#pragma unroll
        for (int q = 0; q < 8; ++q) {
            float x = zr[q]; r[q] = x * x;
#pragma unroll
            for (int m = 1; m < 8; ++m) {
                float y = zr[q + 8 * m];
                float sq = y * y;
                r[q] = r[q] + sq;
            }
        }
        zsq_s[tid] = ((r[0] + r[1]) + (r[2] + r[3])) + ((r[4] + r[5]) + (r[6] + r[7]));
    }
    __syncthreads();
    if (tid < TPB) {
        const float mx = fmaxf(fmaxf(mxw[0][tid], mxw[1][tid]),
                               fmaxf(mxw[2][tid], mxw[3][tid]));
        const float zsq = zsq_s[tid];
        const float eps = sqrtf(zsq) * 4.2e-6f + 2e-7f;   // covers e-bf16 + z-bf16 (no lo)
        eps_s[tid] = eps;
        bD_s[tid] = zsq - 2.0f * mx + 2.0f * eps + DINIT;   // >= true best fl-d
    }
    __syncthreads();

    // ---- phase 1b: survivor masks for this wave's 8 chunks (ballot) ----
#pragma unroll
    for (int i = 0; i < 8; ++i) {
        const int c = 8 * w + i;
        const float mA = bf2f(Mm[(size_t)c * N_TOK + t0 + lane]);
        const int sA = (fmaf(-2.0f, mA + eps_s[lane], zsq_s[lane]) - MRG) < bD_s[lane];
        const unsigned long long b0 = __ballot(sA);
        const float mB = bf2f(Mm[(size_t)c * N_TOK + t0 + 64 + lane]);
        const int sB = (fmaf(-2.0f, mB + eps_s[64 + lane], zsq_s[64 + lane]) - MRG) < bD_s[64 + lane];
        const unsigned long long b1 = __ballot(sB);
        if (lane == 0) { m0_s[c] = b0; m1_s[c] = b1; }
    }
    // no barrier: each wave reads only masks it wrote

    // ---- phase 2: paired eval, 2 tokens per pipelined e-stream ----
    for (int i = 0; i < 8; ++i) {
        const int c = 8 * w + i;
        unsigned long long msk0 = m0_s[c], msk1 = m1_s[c];
        if (!(msk0 | msk1)) continue;
        const int k0 = c * 128 + 2 * lane;
        const float* eb = eT + k0;
        const float2 es2 = *(const float2*)(esq + k0);

        while (msk0 | msk1) {
            int G = 1;
            int tA, tB;
            if (msk0) { tA = __ffsll(msk0) - 1; msk0 &= msk0 - 1; }
            else      { tA = 64 + __ffsll(msk1) - 1; msk1 &= msk1 - 1; }
            tB = tA;
            if (msk0 | msk1) {
                G = 2;
                if (msk0) { tB = __ffsll(msk0) - 1; msk0 &= msk0 - 1; }
                else      { tB = 64 + __ffsll(msk1) - 1; msk1 &= msk1 - 1; }
            }
            const float4* zpA = (const float4*)(&z_s[tA][0]);
            const float4* zpB = (const float4*)(&z_s[tB][0]);

            float2 bA[8], bB[8];
            float aA0, aA1, aB0, aB1;
#define LOADG(B, G2) { _Pragma("unroll") \
    for (int j = 0; j < 8; ++j) \
        B[j] = *(const float2*)(eb + (size_t)(8 * (G2) + j) * K_CODES); }
#define FMAJ(Bj, vA, vB, COMP) \
    aA0 = fmaf(vA.COMP, Bj.x, aA0); aA1 = fmaf(vA.COMP, Bj.y, aA1); \
    aB0 = fmaf(vB.COMP, Bj.x, aB0); aB1 = fmaf(vB.COMP, Bj.y, aB1);
#define FMAG(B, G2) { \
    const float4 vA = zpA[2 * (G2)], vB = zpB[2 * (G2)]; \
    FMAJ(B[0], vA, vB, x) FMAJ(B[1], vA, vB, y) \
    FMAJ(B[2], vA, vB, z) FMAJ(B[3], vA, vB, w) \
    const float4 uA = zpA[2 * (G2) + 1], uB = zpB[2 * (G2) + 1]; \
    FMAJ(B[4], uA, uB, x) FMAJ(B[5], uA, uB, y) \
    FMAJ(B[6], uA, uB, z) FMAJ(B[7], uA, uB, w) }

            LOADG(bA, 0)
            LOADG(bB, 1)
            {   // group 0, j=0 peeled as mul (bitwise head of each chain)
                const float4 vA = zpA[0], vB = zpB[0];
                aA0 = vA.x * bA[0].x; aA1 = vA.x * bA[0].y;
                aB0 = vB.x * bA[0].x; aB1 = vB.x * bA[0].y;
                FMAJ(bA[1], vA, vB, y)
                FMAJ(bA[2], vA, vB, z)
                FMAJ(bA[3], vA, vB, w)
                const float4 uA = zpA[1], uB = zpB[1];
                FMAJ(bA[4], uA, uB, x)
                FMAJ(bA[5], uA, uB, y)
                FMAJ(bA[6], uA, uB, z)
                FMAJ(bA[7], uA, uB, w)
            }
            LOADG(bA, 2) FMAG(bB, 1)
            LOADG(bB, 3) FMAG(bA, 2)
            LOADG(bA, 4) FMAG(bB, 3)
            LOADG(bB, 5) FMAG(bA, 4)
            LOADG(bA, 6) FMAG(bB, 5)
            LOADG(bB, 7) FMAG(bA, 6)
            FMAG(bB, 7)
#undef LOADG
#undef FMAJ
#undef FMAG

#define FINISH(aX0, aX1, tX) { \
    const float zqX = zsq_s[tX]; \
    const float dX0 = fmaf(-2.0f, aX0, zqX + es2.x); \
    const float dX1 = fmaf(-2.0f, aX1, zqX + es2.y); \
    float dl = dX0; int il = k0; \
    if (dX1 < dl) { dl = dX1; il = k0 + 1; } \
    _Pragma("unroll") \
    for (int mm = 1; mm < 64; mm <<= 1) { \
        const float ov = __shfl_xor(dl, mm, 64); \
        const int   oi = __shfl_xor(il, mm, 64); \
        if (ov < dl || (ov == dl && oi < il)) { dl = ov; il = oi; } \
    } \
    if (lane == 0) atomicMin(&key_s[tX], packdi(dl, il)); }

            FINISH(aA0, aA1, tA)
            if (G > 1) FINISH(aB0, aB1, tB)
#undef FINISH
        }
    }
    __syncthreads();

    if (FUSED) {
        // ---- fused vq_finish epilogue: idx, z_q = h + (q - h), loss partial
        //      (per-token chain byte-identical to the proven vq_finish) ----
        if (tid < TPB) {
            const int t = t0 + tid;
            const int bi = (int)(key_s[tid] & 0xFFFFFFFFull);
            out_idx[t] = (float)bi;
            const float4* q4 = (const float4*)(emb + (size_t)bi * DIM);
            const float4* h4 = (const float4*)(&z_s[tid][0]);   // same bits as hid row
            float4* o4 = (float4*)(out_zq + (size_t)t * DIM);
            float lsum = 0.f;
#pragma unroll
            for (int i = 0; i < 16; ++i) {
                const float4 q = q4[i];
                const float4 h = h4[i];
                float4 zq;
                float dx;
                dx = q.x - h.x; zq.x = h.x + dx; lsum += dx * dx;
                dx = q.y - h.y; zq.y = h.y + dx; lsum += dx * dx;
                dx = q.z - h.z; zq.z = h.z + dx; lsum += dx * dx;
                dx = q.w - h.w; zq.w = h.w + dx; lsum += dx * dx;
                o4[i] = zq;
            }
#pragma unroll
            for (int off = 32; off >= 1; off >>= 1) lsum += __shfl_xor(lsum, off, 64);
            if ((tid & 63) == 0) lred[tid >> 6] = lsum;
        }
        __syncthreads();
        if (tid == 0) partials[blockIdx.x] = lred[0] + lred[1];
    } else {
        if (tid < TPB) out_idx[t0 + tid] = (float)(int)(key_s[tid] & 0xFFFFFFFFull);
    }
}

// ---------------------------------------------------------------------------
// Fallback outputs kernel (proven vq_finish) + both loss reducers.
// ---------------------------------------------------------------------------
__global__ __launch_bounds__(256) void vq_finish(const float* __restrict__ hid,
                                                 const float* __restrict__ emb,
                                                 const float* __restrict__ out_idx,
                                                 float* __restrict__ out_zq,
                                                 float* __restrict__ partials) {
#pragma clang fp contract(off)
    __shared__ float lred[4];
    const int tid = threadIdx.x;
    const int t = blockIdx.x * 256 + tid;

    const int bi = (int)out_idx[t];

    const float4* q4 = (const float4*)(emb + (size_t)bi * DIM);
    const float4* h4 = (const float4*)(hid + (size_t)t * DIM);
    float4* o4 = (float4*)(out_zq + (size_t)t * DIM);
    float lsum = 0.f;
#pragma unroll
    for (int i = 0; i < 16; ++i) {
        const float4 q = q4[i];
        const float4 h = h4[i];
        float4 zq;
        float dx;
        dx = q.x - h.x; zq.x = h.x + dx; lsum += dx * dx;
        dx = q.y - h.y; zq.y = h.y + dx; lsum += dx * dx;
        dx = q.z - h.z; zq.z = h.z + dx; lsum += dx * dx;
        dx = q.w - h.w; zq.w = h.w + dx; lsum += dx * dx;
        o4[i] = zq;
    }

#pragma unroll
    for (int off = 32; off >= 1; off >>= 1) lsum += __shfl_xor(lsum, off, 64);
    const int wid = tid >> 6;
    if ((tid & 63) == 0) lred[wid] = lsum;
    __syncthreads();
    if (tid == 0) partials[blockIdx.x] = (lred[0] + lred[1]) + (lred[2] + lred[3]);
}

__global__ __launch_bounds__(128) void loss_kernel128(const float* __restrict__ partials,
                                                      float* __restrict__ out_loss) {
#pragma clang fp contract(off)
    __shared__ float s[128];
    const int t = threadIdx.x;
    s[t] = partials[t];
    __syncthreads();
    for (int off = 64; off >= 1; off >>= 1) {
        if (t < off) s[t] = s[t] + s[t + off];
        __syncthreads();
    }
    if (t == 0) {
        const float m = s[0] * (1.0f / 2097152.0f);  // exact: /2^21
        out_loss[0] = m + 0.25f * m;
    }
}

__global__ __launch_bounds__(128) void loss_kernel256(const float* __restrict__ partials,
                                                      float* __restrict__ out_loss) {
#pragma clang fp contract(off)
    __shared__ float s[128];
    const int t = threadIdx.x;
    s[t] = partials[t] + partials[t + 128];
    __syncthreads();
    for (int off = 64; off >= 1; off >>= 1) {
        if (t < off) s[t] = s[t] + s[t + off];
        __syncthreads();
    }
    if (t == 0) {
        const float m = s[0] * (1.0f / 2097152.0f);  // exact: /2^21
        out_loss[0] = m + 0.25f * m;
    }
}

extern "C" void kernel_launch(void* const* d_in, const int* in_sizes, int n_in,
                              void* d_out, int out_size, void* d_ws, size_t ws_size,
                              hipStream_t stream) {
    const float* hid = (const float*)d_in[0];
    const float* emb = (const float*)d_in[1];
    float* out = (float*)d_out;
    float* ws  = (float*)d_ws;

    if (ws_size >= (size_t)W2_TOTAL * sizeof(float)) {
        // ---- fused path: eT/Mm in ws; select writes zq/idx/loss partials ----
        float*  esq   = ws + W2_ESQ;
        ushort* ehiT  = (ushort*)(ws + W2_EHIT);
        float*  eT    = ws + W2_ET;
        ushort* Mm    = (ushort*)(ws + W2_MM);
        float*  parts = ws + W2_PART;

        esq_kernel<<<K_CODES / 32, 256, 0, stream>>>(emb, esq);
        pack2<<<K_CODES / 256, 256, 0, stream>>>(emb, ehiT, eT);
        vq_mfma<<<N_TOK / 64, 256, 0, stream>>>(hid, ehiT, Mm);
        vq_select_t<1><<<N_TOK / TPB, 512, 0, stream>>>(hid, eT, esq, Mm, emb,
                                                        out, out + IDX_OFF, parts);
        loss_kernel256<<<1, 128, 0, stream>>>(parts, out + LOSS_OFF);
    } else {
        // ---- fallback path: exactly R20 (proven 138 µs) ----
        float*  esq   = ws + WS_ESQ;
        ushort* ehiT  = (ushort*)(ws + WS_EHIT);
        float*  parts = ws + WS_PART;
        float*  eT    = out;                               // zq-region scratch
        ushort* Mm    = (ushort*)(out + 524288);           // zq-region scratch

        esq_kernel<<<K_CODES / 32, 256, 0, stream>>>(emb, esq);
        pack2<<<K_CODES / 256, 256, 0, stream>>>(emb, ehiT, eT);
        vq_mfma<<<N_TOK / 64, 256, 0, stream>>>(hid, ehiT, Mm);
        vq_select_t<0><<<N_TOK / TPB, 512, 0, stream>>>(hid, eT, esq, Mm, emb,
                                                        out, out + IDX_OFF, parts);
        vq_finish<<<N_TOK / 256, 256, 0, stream>>>(hid, emb, out + IDX_OFF, out, parts);
        loss_kernel128<<<1, 128, 0, stream>>>(parts, out + LOSS_OFF);
    }
}